// Round 1
// baseline (173.453 us; speedup 1.0000x reference)
//
#include <hip/hip_runtime.h>

// Problem constants (match reference)
#define DIM 128
#define HID 256
#define ROWS_PER_BLOCK 32
#define ROWS_PER_WAVE 8

__device__ __forceinline__ float tanh_fast(float x) {
    // tanh(x) = 1 - 2/(exp(2x)+1); exp(2x) = exp2(x * 2*log2(e))
    // Sign-correct for all x including +-inf saturation.
    float t = __builtin_amdgcn_exp2f(x * 2.885390081777927f);
    return 1.0f - 2.0f * __builtin_amdgcn_rcpf(t + 1.0f);
}

__device__ __forceinline__ float sigmoid_fast(float x) {
    float t = __builtin_amdgcn_exp2f(-x * 1.4426950408889634f);
    return __builtin_amdgcn_rcpf(1.0f + t);
}

__device__ __forceinline__ float wave_allreduce_sum(float v) {
#pragma unroll
    for (int m = 32; m >= 1; m >>= 1) v += __shfl_xor(v, m, 64);
    return v;
}

// c[j] = b1[j] + sum_d pivot[d] * W1[d][j]
__global__ void k_precompute_c(const float* __restrict__ pivot,
                               const float* __restrict__ W1,
                               const float* __restrict__ b1,
                               float* __restrict__ c) {
    int j = threadIdx.x;  // 256 threads, 1 block
    float acc = b1[j];
#pragma unroll 8
    for (int d = 0; d < DIM; ++d) acc = fmaf(pivot[d], W1[d * HID + j], acc);
    c[j] = acc;
}

__global__ __launch_bounds__(256) void k_main(
    const float* __restrict__ r,      // [B, 128]
    const float* __restrict__ s,      // [B]
    const float* __restrict__ pivot,  // [128]
    const float* __restrict__ W1,     // [128, 256]
    const float* __restrict__ w2,     // [256]
    const float* __restrict__ b2,     // [1]
    const int* __restrict__ n_iter_p, // [1]
    const float* __restrict__ c,      // [256] precomputed
    float* __restrict__ out)          // [B, 128]
{
    __shared__ float rn_s[ROWS_PER_BLOCK][DIM];  // 16 KiB normalized ray dirs

    const int tid  = threadIdx.x;
    const int lane = tid & 63;
    const int wave = tid >> 6;            // 0..3
    const int row0 = blockIdx.x * ROWS_PER_BLOCK;
    const int n_iter = *n_iter_p;

    // ---- Phase 1: load r rows, normalize into LDS (wave owns its 8 rows) ----
#pragma unroll
    for (int q = 0; q < ROWS_PER_WAVE; ++q) {
        const int lr  = wave * ROWS_PER_WAVE + q;
        const int row = row0 + lr;
        float2 v = *(const float2*)&r[row * DIM + lane * 2];
        float ss = v.x * v.x + v.y * v.y;
        ss = wave_allreduce_sum(ss);                 // full row sum of squares
        float inv = __builtin_amdgcn_rsqf(ss);       // 1/||r||
        float2 rn; rn.x = v.x * inv; rn.y = v.y * inv;
        *(float2*)&rn_s[lr][lane * 2] = rn;
    }
    __syncthreads();

    // ---- Phase 2: g = rn @ W1 : wave computes its 8 rows x 256 cols ----
    // lane owns 4 contiguous columns j0..j0+3
    const int j0 = lane * 4;
    float acc[ROWS_PER_WAVE][4];
#pragma unroll
    for (int q = 0; q < ROWS_PER_WAVE; ++q)
#pragma unroll
        for (int k = 0; k < 4; ++k) acc[q][k] = 0.0f;

    const float* w1p = W1 + j0;
#pragma unroll 2
    for (int d = 0; d < DIM; d += 4) {
        float4 wv0 = *(const float4*)(w1p + (d + 0) * HID);
        float4 wv1 = *(const float4*)(w1p + (d + 1) * HID);
        float4 wv2 = *(const float4*)(w1p + (d + 2) * HID);
        float4 wv3 = *(const float4*)(w1p + (d + 3) * HID);
#pragma unroll
        for (int q = 0; q < ROWS_PER_WAVE; ++q) {
            float4 rv = *(const float4*)&rn_s[wave * ROWS_PER_WAVE + q][d];
            acc[q][0] = fmaf(rv.x, wv0.x, fmaf(rv.y, wv1.x, fmaf(rv.z, wv2.x, fmaf(rv.w, wv3.x, acc[q][0]))));
            acc[q][1] = fmaf(rv.x, wv0.y, fmaf(rv.y, wv1.y, fmaf(rv.z, wv2.y, fmaf(rv.w, wv3.y, acc[q][1]))));
            acc[q][2] = fmaf(rv.x, wv0.z, fmaf(rv.y, wv1.z, fmaf(rv.z, wv2.z, fmaf(rv.w, wv3.z, acc[q][2]))));
            acc[q][3] = fmaf(rv.x, wv0.w, fmaf(rv.y, wv1.w, fmaf(rv.z, wv2.w, fmaf(rv.w, wv3.w, acc[q][3]))));
        }
    }

    // ---- Phase 3: 20 ray-march iterations, g resident in registers ----
    const float4 c4 = *(const float4*)&c[j0];
    const float4 w4 = *(const float4*)&w2[j0];
    const float b2v = b2[0];

    float alpha[ROWS_PER_WAVE];
#pragma unroll
    for (int q = 0; q < ROWS_PER_WAVE; ++q) alpha[q] = 0.0f;

    for (int it = 0; it < n_iter; ++it) {
        float p[ROWS_PER_WAVE];
#pragma unroll
        for (int q = 0; q < ROWS_PER_WAVE; ++q) {
            const float a = alpha[q];
            float h0 = tanh_fast(fmaf(a, acc[q][0], c4.x));
            float h1 = tanh_fast(fmaf(a, acc[q][1], c4.y));
            float h2 = tanh_fast(fmaf(a, acc[q][2], c4.z));
            float h3 = tanh_fast(fmaf(a, acc[q][3], c4.w));
            p[q] = fmaf(h0, w4.x, fmaf(h1, w4.y, fmaf(h2, w4.z, h3 * w4.w)));
        }
        // 8 independent butterfly chains — interleaved by the scheduler
#pragma unroll
        for (int q = 0; q < ROWS_PER_WAVE; ++q) {
            float z = wave_allreduce_sum(p[q]) + b2v;
            alpha[q] += 0.05f * (1.0f + tanh_fast(z));
        }
    }

    // ---- Phase 4: out[row] = pivot + sigmoid(s[row]) * alpha * rn ----
    const float2 pv = *(const float2*)&pivot[lane * 2];
#pragma unroll
    for (int q = 0; q < ROWS_PER_WAVE; ++q) {
        const int lr  = wave * ROWS_PER_WAVE + q;
        const int row = row0 + lr;
        const float scale = sigmoid_fast(s[row]) * alpha[q];
        float2 rn = *(const float2*)&rn_s[lr][lane * 2];
        float2 o;
        o.x = fmaf(scale, rn.x, pv.x);
        o.y = fmaf(scale, rn.y, pv.y);
        *(float2*)&out[row * DIM + lane * 2] = o;
    }
}

extern "C" void kernel_launch(void* const* d_in, const int* in_sizes, int n_in,
                              void* d_out, int out_size, void* d_ws, size_t ws_size,
                              hipStream_t stream) {
    const float* r      = (const float*)d_in[0];
    const float* s      = (const float*)d_in[1];
    const float* pivot  = (const float*)d_in[2];
    const float* W1     = (const float*)d_in[3];
    const float* b1     = (const float*)d_in[4];
    const float* w2     = (const float*)d_in[5];
    const float* b2     = (const float*)d_in[6];
    const int*   n_iter = (const int*)d_in[7];
    float* out = (float*)d_out;
    float* c   = (float*)d_ws;  // 256 floats of scratch

    const int B = in_sizes[0] / DIM;  // 32768

    k_precompute_c<<<1, 256, 0, stream>>>(pivot, W1, b1, c);
    k_main<<<B / ROWS_PER_BLOCK, 256, 0, stream>>>(r, s, pivot, W1, w2, b2,
                                                   n_iter, c, out);
}

// Round 2
// 164.215 us; speedup vs baseline: 1.0563x; 1.0563x over previous
//
#include <hip/hip_runtime.h>

// Problem constants (match reference)
#define DIM 128
#define HID 256
#define ROWS_PER_BLOCK 16
#define ROWS_PER_WAVE 4
#define K2LE 2.885390081777927f   // 2*log2(e): tanh(x) = 1 - 2/(exp2(K2LE*x)+1)

__device__ __forceinline__ float sigmoid_fast(float x) {
    float t = __builtin_amdgcn_exp2f(-x * 1.4426950408889634f);
    return __builtin_amdgcn_rcpf(1.0f + t);
}

__device__ __forceinline__ float wave_allreduce_sum(float v) {
#pragma unroll
    for (int m = 32; m >= 1; m >>= 1) v += __shfl_xor(v, m, 64);
    return v;
}

__global__ __launch_bounds__(256, 8) void k_main(
    const float* __restrict__ r,      // [B, 128]
    const float* __restrict__ s,      // [B]
    const float* __restrict__ pivot,  // [128]
    const float* __restrict__ W1,     // [128, 256]
    const float* __restrict__ b1,     // [256]
    const float* __restrict__ w2,     // [256]
    const float* __restrict__ b2,     // [1]
    const int* __restrict__ n_iter_p, // [1]
    float* __restrict__ out)          // [B, 128]
{
    __shared__ float rn_s[ROWS_PER_BLOCK][DIM];  // 8 KiB normalized ray dirs
    __shared__ float piv_s[DIM];                 // 512 B

    const int tid  = threadIdx.x;
    const int lane = tid & 63;
    const int wave = tid >> 6;            // 0..3
    const int row0 = blockIdx.x * ROWS_PER_BLOCK;
    const int n_iter = *n_iter_p;

    // ---- Phase 1: normalize r rows into LDS; stash pivot in LDS ----
    if (tid < 32) {
        float4 pv = *(const float4*)&pivot[tid * 4];
        *(float4*)&piv_s[tid * 4] = pv;
    }
#pragma unroll
    for (int q = 0; q < ROWS_PER_WAVE; ++q) {
        const int lr  = wave * ROWS_PER_WAVE + q;
        const int row = row0 + lr;
        float2 v = *(const float2*)&r[row * DIM + lane * 2];
        float ss = v.x * v.x + v.y * v.y;
        ss = wave_allreduce_sum(ss);
        float inv = __builtin_amdgcn_rsqf(ss);
        float2 rn; rn.x = v.x * inv; rn.y = v.y * inv;
        *(float2*)&rn_s[lr][lane * 2] = rn;
    }
    __syncthreads();

    // ---- Phase 2: g = rn @ W1 (4 rows/wave) and c = pivot @ W1 + b1 ----
    // lane owns 4 contiguous columns j0..j0+3
    const int j0 = lane * 4;
    float acc[ROWS_PER_WAVE][4];
#pragma unroll
    for (int q = 0; q < ROWS_PER_WAVE; ++q)
#pragma unroll
        for (int k = 0; k < 4; ++k) acc[q][k] = 0.0f;
    float4 cacc = *(const float4*)&b1[j0];

    const float* w1p = W1 + j0;
#pragma unroll 2
    for (int d = 0; d < DIM; d += 4) {
        float4 wv0 = *(const float4*)(w1p + (d + 0) * HID);
        float4 wv1 = *(const float4*)(w1p + (d + 1) * HID);
        float4 wv2 = *(const float4*)(w1p + (d + 2) * HID);
        float4 wv3 = *(const float4*)(w1p + (d + 3) * HID);
        float4 pv = *(const float4*)&piv_s[d];
        cacc.x = fmaf(pv.x, wv0.x, fmaf(pv.y, wv1.x, fmaf(pv.z, wv2.x, fmaf(pv.w, wv3.x, cacc.x))));
        cacc.y = fmaf(pv.x, wv0.y, fmaf(pv.y, wv1.y, fmaf(pv.z, wv2.y, fmaf(pv.w, wv3.y, cacc.y))));
        cacc.z = fmaf(pv.x, wv0.z, fmaf(pv.y, wv1.z, fmaf(pv.z, wv2.z, fmaf(pv.w, wv3.z, cacc.z))));
        cacc.w = fmaf(pv.x, wv0.w, fmaf(pv.y, wv1.w, fmaf(pv.z, wv2.w, fmaf(pv.w, wv3.w, cacc.w))));
#pragma unroll
        for (int q = 0; q < ROWS_PER_WAVE; ++q) {
            float4 rv = *(const float4*)&rn_s[wave * ROWS_PER_WAVE + q][d];
            acc[q][0] = fmaf(rv.x, wv0.x, fmaf(rv.y, wv1.x, fmaf(rv.z, wv2.x, fmaf(rv.w, wv3.x, acc[q][0]))));
            acc[q][1] = fmaf(rv.x, wv0.y, fmaf(rv.y, wv1.y, fmaf(rv.z, wv2.y, fmaf(rv.w, wv3.y, acc[q][1]))));
            acc[q][2] = fmaf(rv.x, wv0.z, fmaf(rv.y, wv1.z, fmaf(rv.z, wv2.z, fmaf(rv.w, wv3.z, acc[q][2]))));
            acc[q][3] = fmaf(rv.x, wv0.w, fmaf(rv.y, wv1.w, fmaf(rv.z, wv2.w, fmaf(rv.w, wv3.w, acc[q][3]))));
        }
    }

    // Pre-scale by K2LE so the inner tanh needs no argument multiply.
#pragma unroll
    for (int q = 0; q < ROWS_PER_WAVE; ++q)
#pragma unroll
        for (int k = 0; k < 4; ++k) acc[q][k] *= K2LE;
    const float4 c2 = make_float4(cacc.x * K2LE, cacc.y * K2LE,
                                  cacc.z * K2LE, cacc.w * K2LE);

    // ---- Phase 3: 20 ray-march iterations ----
    // p_row = S - 2*U,  U = sum_j w2_j * rcp(exp2(K*arg_j)+1),  S = sum_j w2_j
    // alpha += 0.05*(1+tanh(p+b2)) = alpha + 0.1 - 0.1*rcp(exp2(fma(-2K,U,C0))+1)
    const float4 w4 = *(const float4*)&w2[j0];
    const float b2v = b2[0];
    const float S  = wave_allreduce_sum(w4.x + w4.y + w4.z + w4.w);
    const float C0 = K2LE * (S + b2v);

    float alpha[ROWS_PER_WAVE];
#pragma unroll
    for (int q = 0; q < ROWS_PER_WAVE; ++q) alpha[q] = 0.0f;

    for (int it = 0; it < n_iter; ++it) {
        float part[ROWS_PER_WAVE];
#pragma unroll
        for (int q = 0; q < ROWS_PER_WAVE; ++q) {
            const float a = alpha[q];
            float u0 = __builtin_amdgcn_rcpf(__builtin_amdgcn_exp2f(fmaf(a, acc[q][0], c2.x)) + 1.0f);
            float u1 = __builtin_amdgcn_rcpf(__builtin_amdgcn_exp2f(fmaf(a, acc[q][1], c2.y)) + 1.0f);
            float u2 = __builtin_amdgcn_rcpf(__builtin_amdgcn_exp2f(fmaf(a, acc[q][2], c2.z)) + 1.0f);
            float u3 = __builtin_amdgcn_rcpf(__builtin_amdgcn_exp2f(fmaf(a, acc[q][3], c2.w)) + 1.0f);
            part[q] = fmaf(w4.x, u0, fmaf(w4.y, u1, fmaf(w4.z, u2, w4.w * u3)));
        }
#pragma unroll
        for (int q = 0; q < ROWS_PER_WAVE; ++q) {
            float U = wave_allreduce_sum(part[q]);
            float v = __builtin_amdgcn_rcpf(__builtin_amdgcn_exp2f(fmaf(-2.0f * K2LE, U, C0)) + 1.0f);
            alpha[q] += fmaf(-0.1f, v, 0.1f);
        }
    }

    // ---- Phase 4: out[row] = pivot + sigmoid(s[row]) * alpha * rn ----
    const float2 pv = *(const float2*)&piv_s[lane * 2];
#pragma unroll
    for (int q = 0; q < ROWS_PER_WAVE; ++q) {
        const int lr  = wave * ROWS_PER_WAVE + q;
        const int row = row0 + lr;
        const float scale = sigmoid_fast(s[row]) * alpha[q];
        float2 rn = *(const float2*)&rn_s[lr][lane * 2];
        float2 o;
        o.x = fmaf(scale, rn.x, pv.x);
        o.y = fmaf(scale, rn.y, pv.y);
        *(float2*)&out[row * DIM + lane * 2] = o;
    }
}

extern "C" void kernel_launch(void* const* d_in, const int* in_sizes, int n_in,
                              void* d_out, int out_size, void* d_ws, size_t ws_size,
                              hipStream_t stream) {
    const float* r      = (const float*)d_in[0];
    const float* s      = (const float*)d_in[1];
    const float* pivot  = (const float*)d_in[2];
    const float* W1     = (const float*)d_in[3];
    const float* b1     = (const float*)d_in[4];
    const float* w2     = (const float*)d_in[5];
    const float* b2     = (const float*)d_in[6];
    const int*   n_iter = (const int*)d_in[7];
    float* out = (float*)d_out;

    const int B = in_sizes[0] / DIM;  // 32768

    k_main<<<B / ROWS_PER_BLOCK, 256, 0, stream>>>(r, s, pivot, W1, b1, w2, b2,
                                                   n_iter, out);
}

// Round 3
// 137.120 us; speedup vs baseline: 1.2650x; 1.1976x over previous
//
#include <hip/hip_runtime.h>

// Problem constants
#define DIM 128
#define HID 256
#define K2LE 2.885390081777927f   // 2*log2(e): tanh(x) = 1 - 2/(exp2(K2LE*x)+1)
#define NTILES 16                 // HID / 16
#define RPW 16                    // rays per wave (MFMA M)
#define WAVES 4
#define RPB (RPW * WAVES)         // 64 rays per block
#define BFPAD 136                 // bf16 LDS row stride (128 + 8): 2-way banks on frag reads

typedef __attribute__((ext_vector_type(8))) short bf16x8;   // 8 bf16 = 4 VGPRs (guide §3)
typedef __attribute__((ext_vector_type(4))) float f32x4;

__device__ __forceinline__ unsigned short f2bf(float f) {
    union { float f; unsigned u; } x; x.f = f;
    unsigned r = x.u + 0x7fffu + ((x.u >> 16) & 1u);   // RNE
    return (unsigned short)(r >> 16);
}

__device__ __forceinline__ float sigmoid_fast(float x) {
    float t = __builtin_amdgcn_exp2f(-x * 1.4426950408889634f);
    return __builtin_amdgcn_rcpf(1.0f + t);
}

// ---------------------------------------------------------------------------
// Prep: c2[j] = K2LE*(pivot@W1 + b1)[j]  (f32, block 0)
//       W1f   = bf16(K2LE*W1) in MFMA B-fragment order:
//               entry e = nt*256 + kk*64 + q*16 + m  holds
//               W1[kk*32+q*8+j][nt*16+m], j=0..7  (16 B per entry)
// Grid: 16 blocks x 256 threads (block b owns nt=b's 256 entries).
// ---------------------------------------------------------------------------
__global__ void k_prep(const float* __restrict__ pivot,
                       const float* __restrict__ W1,
                       const float* __restrict__ b1,
                       float* __restrict__ c2,
                       uint4* __restrict__ W1f) {
    const int tid = threadIdx.x;
    if (blockIdx.x == 0) {
        float a = b1[tid];
#pragma unroll 8
        for (int d = 0; d < DIM; ++d) a = fmaf(pivot[d], W1[d * HID + tid], a);
        c2[tid] = K2LE * a;
    }
    const int e  = blockIdx.x * 256 + tid;
    const int m  = e & 15;
    const int q  = (e >> 4) & 3;
    const int kk = (e >> 6) & 3;
    const int nt = e >> 8;
    const int n  = nt * 16 + m;
    const int k0 = kk * 32 + q * 8;
    unsigned w[4];
#pragma unroll
    for (int p = 0; p < 4; ++p) {
        unsigned lo = f2bf(W1[(k0 + 2 * p    ) * HID + n] * K2LE);
        unsigned hi = f2bf(W1[(k0 + 2 * p + 1) * HID + n] * K2LE);
        w[p] = lo | (hi << 16);
    }
    W1f[e] = make_uint4(w[0], w[1], w[2], w[3]);
}

// ---------------------------------------------------------------------------
// Main: 512 blocks x 256 threads. Wave owns 16 rays end-to-end (no cross-wave
// data sharing except the trivial alpha_s broadcast).
// ---------------------------------------------------------------------------
__global__ __launch_bounds__(256, 2) void k_main(
    const float* __restrict__ r,      // [B, 128]
    const float* __restrict__ s,      // [B]
    const float* __restrict__ pivot,  // [128]
    const float* __restrict__ w2,     // [256]
    const float* __restrict__ b2,     // [1]
    const int* __restrict__ n_iter_p, // [1]
    const float* __restrict__ c2,     // [256] K2LE*(pivot@W1+b1)
    const uint4* __restrict__ W1f,    // frag-ordered bf16 K2LE*W1
    float* __restrict__ out)          // [B, 128]
{
    __shared__ unsigned short rnbf[RPB][BFPAD];   // bf16 rn, padded rows (17.4 KB)
    __shared__ float alpha_s[WAVES][RPW];

    const int tid  = threadIdx.x;
    const int lane = tid & 63;
    const int wave = tid >> 6;
    const int m    = lane & 15;     // MFMA: A-row / B-col / C-col
    const int q    = lane >> 4;     // MFMA quad
    const int rowb = blockIdx.x * RPB + wave * RPW;
    const int n_iter = *n_iter_p;

    // ---- Phase 1: load + normalize 16 rays; keep f32 in regs, bf16 in LDS ----
    float2 rn2[RPW];
#pragma unroll 4
    for (int t = 0; t < RPW; ++t) {
        float2 v = *(const float2*)&r[(rowb + t) * DIM + lane * 2];
        float ss = v.x * v.x + v.y * v.y;
#pragma unroll
        for (int msk = 32; msk >= 1; msk >>= 1) ss += __shfl_xor(ss, msk, 64);
        float inv = __builtin_amdgcn_rsqf(ss);
        rn2[t].x = v.x * inv; rn2[t].y = v.y * inv;
        unsigned pack = (unsigned)f2bf(rn2[t].x) | ((unsigned)f2bf(rn2[t].y) << 16);
        *(unsigned*)&rnbf[wave * RPW + t][lane * 2] = pack;
    }

    // ---- Phase 2: g2 = rn @ (K2LE*W1) via MFMA, f32 acc ----
    // A-frag(kk): rn_bf[ray=m][k = kk*32 + q*8 + j]  (same-wave LDS, no barrier)
    bf16x8 afrag[4];
#pragma unroll
    for (int kk = 0; kk < 4; ++kk)
        afrag[kk] = *(const bf16x8*)&rnbf[wave * RPW + m][kk * 32 + q * 8];

    const bf16x8* __restrict__ wf = (const bf16x8*)W1f;
    const int fb = q * 16 + m;          // lane offset within a (nt,kk) frag group
    f32x4 acc[NTILES];
#pragma unroll
    for (int nt = 0; nt < NTILES; ++nt) {
        f32x4 a = {0.f, 0.f, 0.f, 0.f};
#pragma unroll
        for (int kk = 0; kk < 4; ++kk)
            a = __builtin_amdgcn_mfma_f32_16x16x32_bf16(
                    afrag[kk], wf[nt * 256 + kk * 64 + fb], a, 0, 0, 0);
        acc[nt] = a;   // D layout: col = nt*16 + m, rays q*4 + reg
    }

    // ---- Gather per-lane col params: cols nt*16 + m ----
    float w2f[NTILES], c2f[NTILES];
#pragma unroll
    for (int nt = 0; nt < NTILES; ++nt) {
        w2f[nt] = w2[nt * 16 + m];
        c2f[nt] = c2[nt * 16 + m];
    }
    // S = sum(w2): per-lane partial over nt, butterfly over m (16 lanes)
    float S = 0.f;
#pragma unroll
    for (int nt = 0; nt < NTILES; ++nt) S += w2f[nt];
#pragma unroll
    for (int msk = 1; msk <= 8; msk <<= 1) S += __shfl_xor(S, msk, 64);
    const float C0 = K2LE * (S + b2[0]);

    // ---- Phase 3: n_iter ray-march steps ----
    // unit: u = rcp(exp2(fma(alpha, g2, c2)) + 1);  U_row = sum_cols w2*u
    // alpha += 0.1 - 0.1*rcp(exp2(C0 - 2*K2LE*U) + 1)
    float alpha[4] = {0.f, 0.f, 0.f, 0.f};
    for (int it = 0; it < n_iter; ++it) {
        float part0 = 0.f, part1 = 0.f, part2 = 0.f, part3 = 0.f;
#pragma unroll
        for (int nt = 0; nt < NTILES; ++nt) {
            float u0 = __builtin_amdgcn_rcpf(__builtin_amdgcn_exp2f(fmaf(alpha[0], acc[nt][0], c2f[nt])) + 1.0f);
            float u1 = __builtin_amdgcn_rcpf(__builtin_amdgcn_exp2f(fmaf(alpha[1], acc[nt][1], c2f[nt])) + 1.0f);
            float u2 = __builtin_amdgcn_rcpf(__builtin_amdgcn_exp2f(fmaf(alpha[2], acc[nt][2], c2f[nt])) + 1.0f);
            float u3 = __builtin_amdgcn_rcpf(__builtin_amdgcn_exp2f(fmaf(alpha[3], acc[nt][3], c2f[nt])) + 1.0f);
            part0 = fmaf(w2f[nt], u0, part0);
            part1 = fmaf(w2f[nt], u1, part1);
            part2 = fmaf(w2f[nt], u2, part2);
            part3 = fmaf(w2f[nt], u3, part3);
        }
        // reduce across the 16 lanes of this quad-group (cols) — 4 steps
#pragma unroll
        for (int msk = 1; msk <= 8; msk <<= 1) {
            part0 += __shfl_xor(part0, msk, 64);
            part1 += __shfl_xor(part1, msk, 64);
            part2 += __shfl_xor(part2, msk, 64);
            part3 += __shfl_xor(part3, msk, 64);
        }
        float v0 = __builtin_amdgcn_rcpf(__builtin_amdgcn_exp2f(fmaf(-2.0f * K2LE, part0, C0)) + 1.0f);
        float v1 = __builtin_amdgcn_rcpf(__builtin_amdgcn_exp2f(fmaf(-2.0f * K2LE, part1, C0)) + 1.0f);
        float v2 = __builtin_amdgcn_rcpf(__builtin_amdgcn_exp2f(fmaf(-2.0f * K2LE, part2, C0)) + 1.0f);
        float v3 = __builtin_amdgcn_rcpf(__builtin_amdgcn_exp2f(fmaf(-2.0f * K2LE, part3, C0)) + 1.0f);
        alpha[0] += fmaf(-0.1f, v0, 0.1f);
        alpha[1] += fmaf(-0.1f, v1, 0.1f);
        alpha[2] += fmaf(-0.1f, v2, 0.1f);
        alpha[3] += fmaf(-0.1f, v3, 0.1f);
    }

    // ---- Broadcast alpha (rays q*4+rr live uniformly in group q) ----
    if (m == 0) {
#pragma unroll
        for (int rr = 0; rr < 4; ++rr) alpha_s[wave][q * 4 + rr] = alpha[rr];
    }
    __syncthreads();

    // ---- Phase 4: out[row] = pivot + sigmoid(s[row])*alpha*rn ----
    const float2 pv = *(const float2*)&pivot[lane * 2];
#pragma unroll 4
    for (int t = 0; t < RPW; ++t) {
        const int row = rowb + t;
        const float scale = sigmoid_fast(s[row]) * alpha_s[wave][t];
        float2 o;
        o.x = fmaf(scale, rn2[t].x, pv.x);
        o.y = fmaf(scale, rn2[t].y, pv.y);
        *(float2*)&out[row * DIM + lane * 2] = o;
    }
}

extern "C" void kernel_launch(void* const* d_in, const int* in_sizes, int n_in,
                              void* d_out, int out_size, void* d_ws, size_t ws_size,
                              hipStream_t stream) {
    const float* r      = (const float*)d_in[0];
    const float* s      = (const float*)d_in[1];
    const float* pivot  = (const float*)d_in[2];
    const float* W1     = (const float*)d_in[3];
    const float* b1     = (const float*)d_in[4];
    const float* w2     = (const float*)d_in[5];
    const float* b2     = (const float*)d_in[6];
    const int*   n_iter = (const int*)d_in[7];
    float* out = (float*)d_out;

    float* c2  = (float*)d_ws;                       // 256 f32
    uint4* W1f = (uint4*)((char*)d_ws + 4096);       // 64 KB frag-ordered bf16

    const int B = in_sizes[0] / DIM;  // 32768

    k_prep<<<16, 256, 0, stream>>>(pivot, W1, b1, c2, W1f);
    k_main<<<B / RPB, 256, 0, stream>>>(r, s, pivot, w2, b2, n_iter, c2, W1f, out);
}